// Round 3
// baseline (26.866 us; speedup 1.0000x reference)
//
#include <hip/hip_runtime.h>

// KFIoU loss: per-row 5-float (x,y,w,h,r) pred/target -> smooth-L1 xy loss +
// KF IoU loss. Outputs: [loss.mean, xy_loss.mean, kf_loss.mean, KFIoU*3 (N)].
//
// R1: same-address atomic storm -> partials + reduce kernel.
// R2: 24.4us; row loads (80B/lane stride) gather-bound in L1, not HBM-bound.
// R3: LDS staging — contiguous float4 global loads; scalar LDS row reads are
//     conflict-free (stride 5 dwords, gcd(5,32)=1 -> 2-way = free).

#define BLOCK 256
#define RPB   1024                 // rows staged per block
#define F4PB  (RPB * 5 / 4)        // 1280 float4 per tensor per block

__device__ __forceinline__ void cov_terms(float w, float h, float r,
                                          float& s11, float& s12, float& s22,
                                          float& V) {
    w = fminf(fmaxf(w, 1e-7f), 1e7f);
    h = fminf(fmaxf(h, 1e-7f), 1e7f);
    float sn, cs;
    __sincosf(r, &sn, &cs);
    float sw = 0.25f * w * w;      // (0.5*w)^2
    float sh = 0.25f * h * h;
    s11 = cs * cs * sw + sn * sn * sh;
    s12 = cs * sn * (sw - sh);
    s22 = sn * sn * sw + cs * cs * sh;
    V = w * h;
}

__device__ __forceinline__ float kf_row(const float* P, const float* T,
                                        float& xyl, float& kfl) {
    float dx = fabsf(P[0] - T[0]);
    float dy = fabsf(P[1] - T[1]);
    float lx = dx < 1.0f ? 0.5f * dx * dx : dx - 0.5f;
    float ly = dy < 1.0f ? 0.5f * dy * dy : dy - 0.5f;
    xyl = lx + ly;

    float ap, bp, dp, Vp, at, bt, dt, Vt;
    cov_terms(P[2], P[3], P[4], ap, bp, dp, Vp);
    cov_terms(T[2], T[3], T[4], at, bt, dt, Vt);

    // inv(Sp+St) = adj/det ; K = Sp*inv ; Sigma = Sp - K*Sp
    float A = ap + at, B = bp + bt, D = dp + dt;
    float invdet = 1.0f / (A * D - B * B);
    float K11 = (ap * D - bp * B) * invdet;
    float K12 = (bp * A - ap * B) * invdet;
    float K21 = (bp * D - dp * B) * invdet;
    float K22 = (dp * A - bp * B) * invdet;
    float S11 = ap - (K11 * ap + K12 * bp);
    float S12 = bp - (K11 * bp + K12 * dp);
    float S21 = bp - (K21 * ap + K22 * bp);
    float S22 = dp - (K21 * bp + K22 * dp);
    float detS = S11 * S22 - S12 * S21;
    float Vb = detS > 0.0f ? 4.0f * sqrtf(detS) : 0.0f;
    float kfiou = Vb / (Vp + Vt - Vb + 1e-6f);
    kfl = 1.0f - kfiou;
    return 3.0f * kfiou;
}

__global__ __launch_bounds__(BLOCK) void kf_main(
    const float4* __restrict__ pred4, const float4* __restrict__ tgt4,
    float* __restrict__ out, float* __restrict__ partials, int n)
{
    __shared__ float4 sp4[F4PB];
    __shared__ float4 st4[F4PB];
    float* sp = (float*)sp4;
    float* st = (float*)st4;

    const size_t base_row = (size_t)blockIdx.x * RPB;
    const size_t base_f4  = (size_t)blockIdx.x * F4PB;
    const size_t tot_f4   = ((size_t)n * 5) / 4;   // N=2M -> exact

    // contiguous, fully-coalesced staging: 5 float4 per thread per tensor
#pragma unroll
    for (int j = 0; j < 5; ++j) {
        const int li = threadIdx.x + j * BLOCK;
        const size_t f = base_f4 + li;
        if (f < tot_f4) {
            sp4[li] = pred4[f];
            st4[li] = tgt4[f];
        }
    }
    __syncthreads();

    float sl = 0.f, sx = 0.f, sk = 0.f;
#pragma unroll
    for (int k = 0; k < 4; ++k) {
        const int r = threadIdx.x + k * BLOCK;   // local row
        const size_t gr = base_row + r;
        if (gr < (size_t)n) {
            float P[5], T[5];
#pragma unroll
            for (int j = 0; j < 5; ++j) {        // stride-5 dwords: conflict-free
                P[j] = sp[5 * r + j];
                T[j] = st[5 * r + j];
            }
            float xyl, kfl;
            float k3 = kf_row(P, T, xyl, kfl);
            out[3 + gr] = k3;                    // coalesced dword store
            sl += fmaxf(xyl + kfl, 0.f);
            sx += xyl;
            sk += kfl;
        }
    }

    // wave64 tree reduce (fp32)
#pragma unroll
    for (int off = 32; off > 0; off >>= 1) {
        sl += __shfl_down(sl, off);
        sx += __shfl_down(sx, off);
        sk += __shfl_down(sk, off);
    }
    __shared__ float smem[3][4];
    const int lane = threadIdx.x & 63;
    const int wave = threadIdx.x >> 6;
    if (lane == 0) {
        smem[0][wave] = sl; smem[1][wave] = sx; smem[2][wave] = sk;
    }
    __syncthreads();
    if (threadIdx.x == 0) {
        float a = 0, b = 0, c = 0;
#pragma unroll
        for (int w = 0; w < 4; ++w) { a += smem[0][w]; b += smem[1][w]; c += smem[2][w]; }
        const int np = gridDim.x;
        partials[blockIdx.x]          = a;
        partials[np + blockIdx.x]     = b;
        partials[2 * np + blockIdx.x] = c;
    }
}

__global__ __launch_bounds__(1024) void kf_reduce(
    const float* __restrict__ partials, float* __restrict__ out,
    int npart, double invn)
{
    double a = 0, b = 0, c = 0;
    for (int i = threadIdx.x; i < npart; i += 1024) {
        a += (double)partials[i];
        b += (double)partials[npart + i];
        c += (double)partials[2 * npart + i];
    }
#pragma unroll
    for (int off = 32; off > 0; off >>= 1) {
        a += __shfl_down(a, off);
        b += __shfl_down(b, off);
        c += __shfl_down(c, off);
    }
    __shared__ double smem[3][16];
    const int lane = threadIdx.x & 63;
    const int wave = threadIdx.x >> 6;
    if (lane == 0) {
        smem[0][wave] = a; smem[1][wave] = b; smem[2][wave] = c;
    }
    __syncthreads();
    if (threadIdx.x == 0) {
        double ra = 0, rb = 0, rc = 0;
#pragma unroll
        for (int w = 0; w < 16; ++w) { ra += smem[0][w]; rb += smem[1][w]; rc += smem[2][w]; }
        out[0] = (float)(ra * invn);
        out[1] = (float)(rb * invn);
        out[2] = (float)(rc * invn);
    }
}

extern "C" void kernel_launch(void* const* d_in, const int* in_sizes, int n_in,
                              void* d_out, int out_size, void* d_ws, size_t ws_size,
                              hipStream_t stream) {
    const float4* pred4 = (const float4*)d_in[0];
    const float4* tgt4  = (const float4*)d_in[1];
    float* out = (float*)d_out;
    float* partials = (float*)d_ws;

    const int n = in_sizes[0] / 5;            // 2,000,000
    const int nblocks = (n + RPB - 1) / RPB;  // 1954

    kf_main<<<nblocks, BLOCK, 0, stream>>>(pred4, tgt4, out, partials, n);
    kf_reduce<<<1, 1024, 0, stream>>>(partials, out, nblocks, 1.0 / (double)n);
}

// Round 4
// 23.818 us; speedup vs baseline: 1.1280x; 1.1280x over previous
//
#include <hip/hip_runtime.h>

// KFIoU loss: per-row 5-float (x,y,w,h,r) pred/target -> smooth-L1 xy loss +
// KF IoU loss. Outputs: [loss.mean, xy_loss.mean, kf_loss.mean, KFIoU*3 (N)].
//
// R1: same-address atomic storm -> partials + reduce kernel.       (80us)
// R2: row-quad float4 loads, 80B/lane stride: ~3.1 line-req/row.   (24.4us)
// R3: LDS staging regressed (barrier + ds round trip).             (26.9us)
// R4: 1 row/thread, 20B/lane via memcpy'd dwordx4+dword: 1.25
//     line-req/row (2.5x fewer TA requests than R2), no LDS.

#define NBLK  2048
#define BLOCK 256

__device__ __forceinline__ void cov_terms(float w, float h, float r,
                                          float& s11, float& s12, float& s22,
                                          float& V) {
    w = fminf(fmaxf(w, 1e-7f), 1e7f);
    h = fminf(fmaxf(h, 1e-7f), 1e7f);
    float sn, cs;
    __sincosf(r, &sn, &cs);
    float sw = 0.25f * w * w;      // (0.5*w)^2
    float sh = 0.25f * h * h;
    s11 = cs * cs * sw + sn * sn * sh;
    s12 = cs * sn * (sw - sh);
    s22 = sn * sn * sw + cs * cs * sh;
    V = w * h;
}

__device__ __forceinline__ float kf_row(const float* P, const float* T,
                                        float& xyl, float& kfl) {
    float dx = fabsf(P[0] - T[0]);
    float dy = fabsf(P[1] - T[1]);
    float lx = dx < 1.0f ? 0.5f * dx * dx : dx - 0.5f;
    float ly = dy < 1.0f ? 0.5f * dy * dy : dy - 0.5f;
    xyl = lx + ly;

    float ap, bp, dp, Vp, at, bt, dt, Vt;
    cov_terms(P[2], P[3], P[4], ap, bp, dp, Vp);
    cov_terms(T[2], T[3], T[4], at, bt, dt, Vt);

    // inv(Sp+St) = adj/det ; K = Sp*inv ; Sigma = Sp - K*Sp
    float A = ap + at, B = bp + bt, D = dp + dt;
    float invdet = 1.0f / (A * D - B * B);
    float K11 = (ap * D - bp * B) * invdet;
    float K12 = (bp * A - ap * B) * invdet;
    float K21 = (bp * D - dp * B) * invdet;
    float K22 = (dp * A - bp * B) * invdet;
    float S11 = ap - (K11 * ap + K12 * bp);
    float S12 = bp - (K11 * bp + K12 * dp);
    float S21 = bp - (K21 * ap + K22 * bp);
    float S22 = dp - (K21 * bp + K22 * dp);
    float detS = S11 * S22 - S12 * S21;
    float Vb = detS > 0.0f ? 4.0f * sqrtf(detS) : 0.0f;
    float kfiou = Vb / (Vp + Vt - Vb + 1e-6f);
    kfl = 1.0f - kfiou;
    return 3.0f * kfiou;
}

__global__ __launch_bounds__(BLOCK) void kf_main(
    const float* __restrict__ pred, const float* __restrict__ tgt,
    float* __restrict__ out, float* __restrict__ partials, int n)
{
    const int stride = gridDim.x * blockDim.x;
    float sl = 0.f, sx = 0.f, sk = 0.f;

    for (int i = blockIdx.x * blockDim.x + threadIdx.x; i < n; i += stride) {
        const float* p = pred + 5 * (size_t)i;
        const float* t = tgt  + 5 * (size_t)i;
        float P[5], T[5];
        // 16B vector load (dword-aligned dwordx4 is legal on gfx9+) + scalar
        __builtin_memcpy(P, p, 16);  P[4] = p[4];
        __builtin_memcpy(T, t, 16);  T[4] = t[4];

        float xyl, kfl;
        float k3 = kf_row(P, T, xyl, kfl);
        out[3 + (size_t)i] = k3;     // coalesced dword store
        sl += fmaxf(xyl + kfl, 0.f);
        sx += xyl;
        sk += kfl;
    }

    // wave64 tree reduce (fp32)
#pragma unroll
    for (int off = 32; off > 0; off >>= 1) {
        sl += __shfl_down(sl, off);
        sx += __shfl_down(sx, off);
        sk += __shfl_down(sk, off);
    }
    __shared__ float smem[3][4];
    const int lane = threadIdx.x & 63;
    const int wave = threadIdx.x >> 6;
    if (lane == 0) {
        smem[0][wave] = sl; smem[1][wave] = sx; smem[2][wave] = sk;
    }
    __syncthreads();
    if (threadIdx.x == 0) {
        float a = 0, b = 0, c = 0;
#pragma unroll
        for (int w = 0; w < 4; ++w) { a += smem[0][w]; b += smem[1][w]; c += smem[2][w]; }
        const int np = gridDim.x;
        partials[blockIdx.x]          = a;
        partials[np + blockIdx.x]     = b;
        partials[2 * np + blockIdx.x] = c;
    }
}

__global__ __launch_bounds__(1024) void kf_reduce(
    const float* __restrict__ partials, float* __restrict__ out,
    int npart, double invn)
{
    double a = 0, b = 0, c = 0;
    for (int i = threadIdx.x; i < npart; i += 1024) {
        a += (double)partials[i];
        b += (double)partials[npart + i];
        c += (double)partials[2 * npart + i];
    }
#pragma unroll
    for (int off = 32; off > 0; off >>= 1) {
        a += __shfl_down(a, off);
        b += __shfl_down(b, off);
        c += __shfl_down(c, off);
    }
    __shared__ double smem[3][16];
    const int lane = threadIdx.x & 63;
    const int wave = threadIdx.x >> 6;
    if (lane == 0) {
        smem[0][wave] = a; smem[1][wave] = b; smem[2][wave] = c;
    }
    __syncthreads();
    if (threadIdx.x == 0) {
        double ra = 0, rb = 0, rc = 0;
#pragma unroll
        for (int w = 0; w < 16; ++w) { ra += smem[0][w]; rb += smem[1][w]; rc += smem[2][w]; }
        out[0] = (float)(ra * invn);
        out[1] = (float)(rb * invn);
        out[2] = (float)(rc * invn);
    }
}

extern "C" void kernel_launch(void* const* d_in, const int* in_sizes, int n_in,
                              void* d_out, int out_size, void* d_ws, size_t ws_size,
                              hipStream_t stream) {
    const float* pred = (const float*)d_in[0];
    const float* tgt  = (const float*)d_in[1];
    float* out = (float*)d_out;
    float* partials = (float*)d_ws;   // 3 * NBLK floats

    const int n = in_sizes[0] / 5;    // 2,000,000

    kf_main<<<NBLK, BLOCK, 0, stream>>>(pred, tgt, out, partials, n);
    kf_reduce<<<1, 1024, 0, stream>>>(partials, out, NBLK, 1.0 / (double)n);
}

// Round 5
// 22.759 us; speedup vs baseline: 1.1804x; 1.0465x over previous
//
#include <hip/hip_runtime.h>

// KFIoU loss: per-row 5-float (x,y,w,h,r) pred/target -> smooth-L1 xy loss +
// KF IoU loss. Outputs: [loss.mean, xy_loss.mean, kf_loss.mean, KFIoU*3 (N)].
//
// R1: same-address atomic storm -> partials + reduce kernel.       (80us)
// R2: row-quad float4 loads.                                       (24.4us)
// R3: LDS staging regressed.                                       (26.9us)
// R4: 20B/lane dwordx4+dword loads == R2 -> loads not the limiter. (23.8us)
// R5: kill the VALU: (a) hw v_sin/v_cos on 2r (replaces ocml sincos
//     w/ Payne-Hanek, ~150 ops/row); (b) det identity
//     det(Sigma) = detSp*detSt/det(Sp+St), detSp=(wh/4)^2 ->
//     Vb = 0.25*Vp*Vt*rsqrt(det(Sp+St)); whole K/Sigma block gone.

#define NBLK  2048
#define BLOCK 256

__device__ __forceinline__ void cov_terms(float w, float h, float r,
                                          float& s11, float& s12, float& s22,
                                          float& V) {
    w = fminf(fmaxf(w, 1e-7f), 1e7f);
    h = fminf(fmaxf(h, 1e-7f), 1e7f);
    const float sw = 0.25f * w * w;        // (0.5*w)^2
    const float sh = 0.25f * h * h;
    const float htr = 0.5f * (sw + sh);
    const float hdf = 0.5f * (sw - sh);
    // s11 = c^2 sw + s^2 sh = htr + cos(2r)*hdf ; s12 = cs(sw-sh) = sin(2r)*hdf
    // hw trig: v_sin/cos compute sin(2*pi*x); want 2r -> x = r/pi. |x|<=1.3: in range.
    const float x = r * 0.3183098861837907f;
    const float s2 = __builtin_amdgcn_sinf(x);
    const float c2 = __builtin_amdgcn_cosf(x);
    s11 = fmaf(c2, hdf, htr);
    s22 = fmaf(-c2, hdf, htr);
    s12 = s2 * hdf;
    V = w * h;
}

__device__ __forceinline__ float kf_row(const float* P, const float* T,
                                        float& xyl, float& kfl) {
    const float dx = fabsf(P[0] - T[0]);
    const float dy = fabsf(P[1] - T[1]);
    const float lx = dx < 1.0f ? 0.5f * dx * dx : dx - 0.5f;
    const float ly = dy < 1.0f ? 0.5f * dy * dy : dy - 0.5f;
    xyl = lx + ly;

    float ap, bp, dp, Vp, at, bt, dt, Vt;
    cov_terms(P[2], P[3], P[4], ap, bp, dp, Vp);
    cov_terms(T[2], T[3], T[4], at, bt, dt, Vt);

    // det(Sp+St); Sigma = Sp(Sp+St)^-1 St  =>  detS = detSp*detSt/detSum,
    // detSp = (Vp/4)^2  =>  Vb = 4*sqrt(detS) = 0.25*Vp*Vt*rsqrt(detSum)
    const float A = ap + at, B = bp + bt, D = dp + dt;
    const float detSum = fmaf(A, D, -B * B);
    float Vb = (detSum > 0.0f)
                   ? 0.25f * Vp * Vt * __builtin_amdgcn_rsqf(detSum)
                   : 0.0f;
    const float kfiou = Vb * __builtin_amdgcn_rcpf(Vp + Vt - Vb + 1e-6f);
    kfl = 1.0f - kfiou;
    return 3.0f * kfiou;
}

__global__ __launch_bounds__(BLOCK) void kf_main(
    const float* __restrict__ pred, const float* __restrict__ tgt,
    float* __restrict__ out, float* __restrict__ partials, int n)
{
    const int stride = gridDim.x * blockDim.x;
    float sl = 0.f, sx = 0.f, sk = 0.f;

    for (int i = blockIdx.x * blockDim.x + threadIdx.x; i < n; i += stride) {
        const float* p = pred + 5 * (size_t)i;
        const float* t = tgt  + 5 * (size_t)i;
        float P[5], T[5];
        // 16B vector load (dword-aligned dwordx4 is legal on gfx9+) + scalar
        __builtin_memcpy(P, p, 16);  P[4] = p[4];
        __builtin_memcpy(T, t, 16);  T[4] = t[4];

        float xyl, kfl;
        const float k3 = kf_row(P, T, xyl, kfl);
        out[3 + (size_t)i] = k3;     // coalesced dword store
        sl += fmaxf(xyl + kfl, 0.f);
        sx += xyl;
        sk += kfl;
    }

    // wave64 tree reduce (fp32)
#pragma unroll
    for (int off = 32; off > 0; off >>= 1) {
        sl += __shfl_down(sl, off);
        sx += __shfl_down(sx, off);
        sk += __shfl_down(sk, off);
    }
    __shared__ float smem[3][4];
    const int lane = threadIdx.x & 63;
    const int wave = threadIdx.x >> 6;
    if (lane == 0) {
        smem[0][wave] = sl; smem[1][wave] = sx; smem[2][wave] = sk;
    }
    __syncthreads();
    if (threadIdx.x == 0) {
        float a = 0, b = 0, c = 0;
#pragma unroll
        for (int w = 0; w < 4; ++w) { a += smem[0][w]; b += smem[1][w]; c += smem[2][w]; }
        const int np = gridDim.x;
        partials[blockIdx.x]          = a;
        partials[np + blockIdx.x]     = b;
        partials[2 * np + blockIdx.x] = c;
    }
}

__global__ __launch_bounds__(1024) void kf_reduce(
    const float* __restrict__ partials, float* __restrict__ out,
    int npart, double invn)
{
    double a = 0, b = 0, c = 0;
    for (int i = threadIdx.x; i < npart; i += 1024) {
        a += (double)partials[i];
        b += (double)partials[npart + i];
        c += (double)partials[2 * npart + i];
    }
#pragma unroll
    for (int off = 32; off > 0; off >>= 1) {
        a += __shfl_down(a, off);
        b += __shfl_down(b, off);
        c += __shfl_down(c, off);
    }
    __shared__ double smem[3][16];
    const int lane = threadIdx.x & 63;
    const int wave = threadIdx.x >> 6;
    if (lane == 0) {
        smem[0][wave] = a; smem[1][wave] = b; smem[2][wave] = c;
    }
    __syncthreads();
    if (threadIdx.x == 0) {
        double ra = 0, rb = 0, rc = 0;
#pragma unroll
        for (int w = 0; w < 16; ++w) { ra += smem[0][w]; rb += smem[1][w]; rc += smem[2][w]; }
        out[0] = (float)(ra * invn);
        out[1] = (float)(rb * invn);
        out[2] = (float)(rc * invn);
    }
}

extern "C" void kernel_launch(void* const* d_in, const int* in_sizes, int n_in,
                              void* d_out, int out_size, void* d_ws, size_t ws_size,
                              hipStream_t stream) {
    const float* pred = (const float*)d_in[0];
    const float* tgt  = (const float*)d_in[1];
    float* out = (float*)d_out;
    float* partials = (float*)d_ws;   // 3 * NBLK floats

    const int n = in_sizes[0] / 5;    // 2,000,000

    kf_main<<<NBLK, BLOCK, 0, stream>>>(pred, tgt, out, partials, n);
    kf_reduce<<<1, 1024, 0, stream>>>(partials, out, NBLK, 1.0 / (double)n);
}